// Round 1
// baseline (254.630 us; speedup 1.0000x reference)
//
#include <hip/hip_runtime.h>
#include <cstdint>
#include <cstddef>

// Problem constants (from reference setup_inputs): x[B=32, T=4096, N=256] fp32.
#define BB 32
#define TT 4096
#define NN 256
#define CC 128          // chunk length along T
#define PP (TT / CC)    // 32 chunks per chain

// State representation: na = "next allowed spike step index" within the chunk.
// Entry state q=k  <=>  na=k (first k steps blocked).
// Spike at step j iff (x>0 && j>=na); then na = j+6 (REFRACTORY_PERIOD=5 blocks
// steps j+1..j+5). Exit q = max(0, na - C)  (always <= 5).

// Pass 1: for each (b, chunk p, n) compute exit states for all 6 entry states,
// packed as 6 nibbles in a u32.
__global__ __launch_bounds__(256) void pass1_exits(const float* __restrict__ x,
                                                   uint32_t* __restrict__ exits) {
    const int n = threadIdx.x;        // 0..255, fastest -> coalesced
    const int p = blockIdx.x;         // chunk
    const int b = blockIdx.y;         // batch
    const float* xp = x + ((size_t)b * TT + (size_t)p * CC) * NN + n;

    int na0 = 0, na1 = 1, na2 = 2, na3 = 3, na4 = 4, na5 = 5;
    #pragma unroll 8
    for (int j = 0; j < CC; ++j) {
        const bool pos = xp[(size_t)j * NN] > 0.0f;
        const int nj = j + 6;
        if (pos & (j >= na0)) na0 = nj;
        if (pos & (j >= na1)) na1 = nj;
        if (pos & (j >= na2)) na2 = nj;
        if (pos & (j >= na3)) na3 = nj;
        if (pos & (j >= na4)) na4 = nj;
        if (pos & (j >= na5)) na5 = nj;
    }
    const uint32_t q0 = (uint32_t)(na0 > CC ? na0 - CC : 0);
    const uint32_t q1 = (uint32_t)(na1 > CC ? na1 - CC : 0);
    const uint32_t q2 = (uint32_t)(na2 > CC ? na2 - CC : 0);
    const uint32_t q3 = (uint32_t)(na3 > CC ? na3 - CC : 0);
    const uint32_t q4 = (uint32_t)(na4 > CC ? na4 - CC : 0);
    const uint32_t q5 = (uint32_t)(na5 > CC ? na5 - CC : 0);
    const uint32_t packed = q0 | (q1 << 4) | (q2 << 8) | (q3 << 12) |
                            (q4 << 16) | (q5 << 20);
    exits[((size_t)b * PP + p) * NN + n] = packed;
}

// Pass 2: sequential composition over the 32 chunks of each chain (8192 chains,
// one thread each). Writes the true entry state per (b, p, n).
__global__ __launch_bounds__(256) void pass2_scan(const uint32_t* __restrict__ exits,
                                                  uint8_t* __restrict__ entry) {
    const int n = threadIdx.x;
    const int b = blockIdx.x;
    int q = 0;  // q0 = 0 at t=0 (reference)
    #pragma unroll
    for (int p = 0; p < PP; ++p) {
        const size_t idx = ((size_t)b * PP + p) * NN + n;
        entry[idx] = (uint8_t)q;
        const uint32_t e = exits[idx];
        q = (int)((e >> (4 * q)) & 0xFu);
    }
}

// Pass 3: with the true entry state known, re-simulate each chunk and emit z.
__global__ __launch_bounds__(256) void pass3_emit(const float* __restrict__ x,
                                                  const uint8_t* __restrict__ entry,
                                                  float* __restrict__ z) {
    const int n = threadIdx.x;
    const int p = blockIdx.x;
    const int b = blockIdx.y;
    const size_t base = ((size_t)b * TT + (size_t)p * CC) * NN + n;
    int na = (int)entry[((size_t)b * PP + p) * NN + n];
    #pragma unroll 8
    for (int j = 0; j < CC; ++j) {
        const bool pos = x[base + (size_t)j * NN] > 0.0f;
        const bool sp = pos & (j >= na);
        z[base + (size_t)j * NN] = sp ? 1.0f : 0.0f;
        if (sp) na = j + 6;
    }
}

extern "C" void kernel_launch(void* const* d_in, const int* in_sizes, int n_in,
                              void* d_out, int out_size, void* d_ws, size_t ws_size,
                              hipStream_t stream) {
    const float* x = (const float*)d_in[0];
    float* z = (float*)d_out;

    // Workspace layout: exits (u32, B*P*N = 1 MiB) then entry (u8, 256 KiB).
    uint32_t* exits = (uint32_t*)d_ws;
    uint8_t* entry = (uint8_t*)((char*)d_ws + (size_t)BB * PP * NN * sizeof(uint32_t));

    dim3 grid1(PP, BB);   // (chunk, batch)
    pass1_exits<<<grid1, 256, 0, stream>>>(x, exits);
    pass2_scan<<<BB, 256, 0, stream>>>(exits, entry);
    pass3_emit<<<grid1, 256, 0, stream>>>(x, entry, z);
}

// Round 2
// 245.689 us; speedup vs baseline: 1.0364x; 1.0364x over previous
//
#include <hip/hip_runtime.h>
#include <cstdint>
#include <cstddef>

// x[B=32, T=4096, N=256] fp32 -> z same shape.
// Refractory scan: spike at step t iff x>0 and t >= na; then na = t+6.
// Entry state q==k  <=>  first k steps of chunk blocked (na=k). q in [0,5].
#define BB 32
#define TT 4096
#define NNV 64        // float4 groups per row (N=256)
#define CC 128        // chunk length (per-thread scan)
#define PSUB 4        // chunks handled per block (one per 64-thread group)
#define PG 8          // chunk-groups per chain: T / (CC*PSUB) = 8
#define MSG_WORDS 32  // 256 chains * 4-bit state / 8 per u32

__global__ __launch_bounds__(256) void refrac_fused(const float* __restrict__ x,
                                                    float* __restrict__ z,
                                                    uint32_t* __restrict__ msg) {
    const int tid = threadIdx.x;
    const int pg = blockIdx.x >> 5;   // chunk-group (time-major dispatch)
    const int b  = blockIdx.x & 31;   // batch
    const int psub = tid >> 6;        // which of the 4 chunks in this group
    const int n4 = tid & 63;          // float4 group along N
    const int p = pg * PSUB + psub;   // absolute chunk index

    const float4* __restrict__ xv = reinterpret_cast<const float4*>(x)
        + ((size_t)b * TT + (size_t)p * CC) * NNV + n4;

    // --- Phase 1: scan chunk for all 6 entry states; stash sign bits ---
    int na[4][6];
    #pragma unroll
    for (int c = 0; c < 4; ++c)
        #pragma unroll
        for (int e = 0; e < 6; ++e) na[c][e] = e;

    uint32_t bits[4][4];  // [chain][word], 128 bits per chain

    #pragma unroll
    for (int w = 0; w < 4; ++w) {
        uint32_t cur[4] = {0u, 0u, 0u, 0u};
        for (int jb = 0; jb < 32; jb += 8) {   // dynamic: keeps code size sane
            float4 buf[8];
            #pragma unroll
            for (int u = 0; u < 8; ++u)
                buf[u] = xv[(size_t)(w * 32 + jb + u) * NNV];
            #pragma unroll
            for (int u = 0; u < 8; ++u) {
                const int j2 = jb + u;         // bit position in word w
                const int j  = w * 32 + j2;    // step within chunk
                const float4 v = buf[u];
                const float fv[4] = {v.x, v.y, v.z, v.w};
                #pragma unroll
                for (int c = 0; c < 4; ++c) {
                    const bool pos = fv[c] > 0.0f;
                    cur[c] |= pos ? (1u << j2) : 0u;
                    #pragma unroll
                    for (int e = 0; e < 6; ++e)
                        if (pos & (j >= na[c][e])) na[c][e] = j + 6;
                }
            }
        }
        #pragma unroll
        for (int c = 0; c < 4; ++c) bits[c][w] = cur[c];
    }

    // Pack exit table (6 nibbles) per chain into LDS.
    __shared__ uint32_t tbl_lds[PSUB][256];
    __shared__ uint8_t  ent_lds[PSUB][256];
    __shared__ uint8_t  sout_lds[256];

    #pragma unroll
    for (int c = 0; c < 4; ++c) {
        uint32_t tbl = 0;
        #pragma unroll
        for (int e = 0; e < 6; ++e) {
            int q = na[c][e] - CC;
            q = q > 0 ? q : 0;                 // exit state in [0,5]
            tbl |= (uint32_t)q << (4 * e);
        }
        tbl_lds[psub][n4 * 4 + c] = tbl;
    }
    __syncthreads();

    // --- Phase 2: resolve true entry states (thread n handles chain n) ---
    {
        const int n = tid;
        int e = 0;
        if (pg > 0) {
            const uint32_t* inw = msg + ((size_t)b * PG + (pg - 1)) * MSG_WORDS + (n >> 3);
            uint32_t wv;
            // nibble bit3 set (poison 0xA) => not ready; states <=5 are valid
            while ((wv = __hip_atomic_load(inw, __ATOMIC_RELAXED,
                                           __HIP_MEMORY_SCOPE_AGENT)) & 0x88888888u)
                __builtin_amdgcn_s_sleep(1);
            e = (int)((wv >> ((n & 7) * 4)) & 0xFu);
        }
        #pragma unroll
        for (int s = 0; s < PSUB; ++s) {
            ent_lds[s][n] = (uint8_t)e;
            e = (int)((tbl_lds[s][n] >> (4 * e)) & 0xFu);
        }
        sout_lds[n] = (uint8_t)e;              // exit of last chunk in group
    }
    __syncthreads();

    if (pg < PG - 1 && tid < MSG_WORDS) {
        uint32_t wv = 0;
        #pragma unroll
        for (int k = 0; k < 8; ++k)
            wv |= (uint32_t)sout_lds[tid * 8 + k] << (4 * k);
        __hip_atomic_store(msg + ((size_t)b * PG + pg) * MSG_WORDS + tid, wv,
                           __ATOMIC_RELAXED, __HIP_MEMORY_SCOPE_AGENT);
    }

    // --- Phase 3: emit z from register bits + resolved entry ---
    float4* __restrict__ zv = reinterpret_cast<float4*>(z)
        + ((size_t)b * TT + (size_t)p * CC) * NNV + n4;

    int ea[4];
    #pragma unroll
    for (int c = 0; c < 4; ++c) ea[c] = (int)ent_lds[psub][n4 * 4 + c];

    #pragma unroll
    for (int w = 0; w < 4; ++w) {
        const uint32_t bw[4] = {bits[0][w], bits[1][w], bits[2][w], bits[3][w]};
        for (int j2 = 0; j2 < 32; ++j2) {
            const int j = w * 32 + j2;
            float o[4];
            #pragma unroll
            for (int c = 0; c < 4; ++c) {
                const bool sp = (((bw[c] >> j2) & 1u) != 0u) & (j >= ea[c]);
                if (sp) ea[c] = j + 6;
                o[c] = sp ? 1.0f : 0.0f;
            }
            zv[(size_t)j * NNV] = make_float4(o[0], o[1], o[2], o[3]);
        }
    }
}

extern "C" void kernel_launch(void* const* d_in, const int* in_sizes, int n_in,
                              void* d_out, int out_size, void* d_ws, size_t ws_size,
                              hipStream_t stream) {
    const float* x = (const float*)d_in[0];
    float* z = (float*)d_out;
    uint32_t* msg = (uint32_t*)d_ws;

    // Deterministic "not ready" poison for the message area each call.
    hipMemsetAsync(d_ws, 0xAA, (size_t)BB * PG * MSG_WORDS * sizeof(uint32_t), stream);

    refrac_fused<<<dim3(BB * PG), 256, 0, stream>>>(x, z, msg);
}